// Round 11
// baseline (197.741 us; speedup 1.0000x reference)
//
#include <hip/hip_runtime.h>
#include <hip/hip_bf16.h>
#include <math.h>

#define B_ 2
#define S_ 2048
#define D_ 1024
#define H_ 16
#define HKV_ 4
#define DH_ 64
#define NTOK (B_*S_)     // 4096
#define NQK 1280         // q(1024) + k(256) fused cols
#define NQKV 1536        // + v

typedef __attribute__((ext_vector_type(8))) short short8;
typedef __attribute__((ext_vector_type(4))) float floatx4;
typedef __attribute__((ext_vector_type(16))) float floatx16;

__device__ __forceinline__ short f2bf(float f) {
    union { __hip_bfloat16 h; short s; } u;
    u.h = __float2bfloat16(f);
    return u.s;
}
__device__ __forceinline__ float bf2f(short s) {
    union { __hip_bfloat16 h; short t; } u;
    u.t = s;
    return __bfloat162float(u.h);
}
__device__ __forceinline__ unsigned fbits(float f) {
    union { float f; unsigned u; } u; u.f = f; return u.u;
}
// pack hi16(a) | hi16(b)<<16 in ONE v_perm_b32 (RTZ bf16 truncation)
__device__ __forceinline__ unsigned packhi(float a, float b) {
    return __builtin_amdgcn_perm(fbits(b), fbits(a), 0x07060302u);
}

__device__ __forceinline__ void gload_lds16(const void* g, void* l) {
    __builtin_amdgcn_global_load_lds(
        (const __attribute__((address_space(1))) void*)g,
        (__attribute__((address_space(3))) void*)l, 16, 0, 0);
}

// ---------------- fused prep: x->bf16 convert + 4 weight transposes --------
__global__ __launch_bounds__(256) void prep_kernel(
    const float* __restrict__ x,  const float* __restrict__ Wq,
    const float* __restrict__ Wk, const float* __restrict__ Wv,
    const float* __restrict__ Wo,
    short* __restrict__ xb, short* __restrict__ wt, short* __restrict__ woT)
{
    int bid = blockIdx.x;
    if (bid < 4096) {
        int i = bid * 256 + threadIdx.x;
        float4 v = ((const float4*)x)[i];
        short4 o = { f2bf(v.x), f2bf(v.y), f2bf(v.z), f2bf(v.w) };
        ((short4*)xb)[i] = o;
        return;
    }
    bid -= 4096;
    const float* src; short* dst; int N;
    if (bid < 1024)      { src = Wq; dst = wt;                        N = 1024; }
    else if (bid < 1280) { bid -= 1024; src = Wk; dst = wt + (size_t)1024 * 1024; N = 256; }
    else if (bid < 1536) { bid -= 1280; src = Wv; dst = wt + (size_t)1280 * 1024; N = 256; }
    else                 { bid -= 1536; src = Wo; dst = woT;          N = 1024; }
    __shared__ float t[32][33];
    int tiles_n = N / 32;
    int n0 = (bid % tiles_n) * 32, k0 = (bid / tiles_n) * 32;
    int tx = threadIdx.x & 31, ty = threadIdx.x >> 5;
    #pragma unroll
    for (int i = 0; i < 4; ++i)
        t[ty + 8 * i][tx] = src[(size_t)(k0 + ty + 8 * i) * N + n0 + tx];
    __syncthreads();
    #pragma unroll
    for (int i = 0; i < 4; ++i)
        dst[(size_t)(n0 + ty + 8 * i) * 1024 + k0 + tx] = f2bf(t[tx][ty + 8 * i]);
}

// ---------------- GEMM: C[M,N] = A[M,1024] @ Bt[N,1024]^T (bf16 MFMA) -------
// 64x128 tile, BK=32, 256 thr = 4 waves as 2x2 -> wave 32 rows x 64 cols
// (acc 2x4). 3-stage LDS ring, counted vmcnt(3). Both-sides chunk swizzle
// (c ^ ((r>>1)&3)) keeps ds_read 2-way (free).
// MODE 2: K region fuses RoPE in-register in the epilogue; V region stores
// transposed with pi^-1 token permutation (attn PV B-operand pure-register).
template<int MODE>
__global__ __launch_bounds__(256, 4) void gemm_tn_kernel(
    const short* __restrict__ A, const short* __restrict__ Bt,
    short* __restrict__ Cb, float* __restrict__ Cf, short* __restrict__ Ct,
    int ldc, const int* __restrict__ poff)
{
    __shared__ short As[3][64 * 32];
    __shared__ short Bs[3][128 * 32];
    const int K = 1024;
    const int tid = threadIdx.x;
    const int bm0 = blockIdx.y * 64;
    const int bn0 = blockIdx.x * 128;
    const int lane = tid & 63, w = tid >> 6;
    const int wm = (w >> 1) * 32, wn = (w & 1) * 64;
    const int lm = lane & 15, quad = lane >> 4;

    floatx4 acc[2][4] = {};

    const int r0  = tid >> 2;                       // staged row 0..63
    const int kb0 = (((tid & 3) ^ ((r0 >> 1) & 3)) ) * 16;  // swizzled src chunk (bytes)

    auto stage = [&](int kt, int buf) {
        const char* gaA = (const char*)A  + ((size_t)(bm0 + r0) * K + kt) * 2 + kb0;
        const char* gaB = (const char*)Bt + ((size_t)(bn0 + r0) * K + kt) * 2 + kb0;
        gload_lds16(gaA,                      (char*)As[buf] + tid * 16);
        gload_lds16(gaB,                      (char*)Bs[buf] + tid * 16);
        gload_lds16(gaB + (size_t)64 * K * 2, (char*)Bs[buf] + 4096 + tid * 16);
    };

    const int swr = (lm >> 1) & 3;

    stage(0, 0);
    stage(32, 1);
    for (int kt = 0; kt < K; kt += 32) {
        const int it = kt >> 5;
        const int buf = it % 3;
        if (it < (K / 32) - 1) asm volatile("s_waitcnt vmcnt(3)" ::: "memory");
        else                   asm volatile("s_waitcnt vmcnt(0)" ::: "memory");
        asm volatile("s_barrier" ::: "memory");
        if (kt + 64 < K) stage(kt + 64, (it + 2) % 3);

        short8 af[2], bfr[4];
        #pragma unroll
        for (int mt = 0; mt < 2; ++mt)
            af[mt] = *(const short8*)&As[buf][(wm + mt * 16 + lm) * 32 + ((quad ^ swr) * 8)];
        #pragma unroll
        for (int nt = 0; nt < 4; ++nt)
            bfr[nt] = *(const short8*)&Bs[buf][(wn + nt * 16 + lm) * 32 + ((quad ^ swr) * 8)];
        #pragma unroll
        for (int mt = 0; mt < 2; ++mt)
            #pragma unroll
            for (int nt = 0; nt < 4; ++nt)
                acc[mt][nt] = __builtin_amdgcn_mfma_f32_16x16x32_bf16(
                    af[mt], bfr[nt], acc[mt][nt], 0, 0, 0);
    }

    const int col_base = bn0 + wn;
    const int row_base = bm0 + wm;
    if (MODE == 2 && bn0 >= NQK) {  // V tiles -> transposed, pi^-1-permuted store
        #pragma unroll
        for (int mt = 0; mt < 2; ++mt)
            #pragma unroll
            for (int nt = 0; nt < 4; ++nt) {
                int vcol = col_base + nt * 16 + lm - NQK;
                int row0 = row_base + mt * 16 + quad * 4;
                // pi^-1 within 64: bit2 = old bit5, bits3..5 = old bits2..4
                int prow = (row0 & ~60) | ((row0 & 32) >> 3) | ((row0 & 0x1C) << 1);
                short4 o = { f2bf(acc[mt][nt][0]), f2bf(acc[mt][nt][1]),
                             f2bf(acc[mt][nt][2]), f2bf(acc[mt][nt][3]) };
                *(short4*)&Ct[(size_t)vcol * NTOK + prow] = o;
            }
    } else if (MODE == 1) {
        #pragma unroll
        for (int mt = 0; mt < 2; ++mt)
            #pragma unroll
            for (int nt = 0; nt < 4; ++nt)
                #pragma unroll
                for (int r = 0; r < 4; ++r) {
                    int row = row_base + mt * 16 + quad * 4 + r;
                    int col = col_base + nt * 16 + lm;
                    Cf[(size_t)row * ldc + col] = acc[mt][nt][r];
                }
    } else {
        if (MODE == 2 && bn0 >= 1024) {
            // K region: fused RoPE. p = nt*16+lm (<32) pairs with p+32 = nt+2.
            #pragma unroll
            for (int mt = 0; mt < 2; ++mt)
                #pragma unroll
                for (int r = 0; r < 4; ++r) {
                    int row = row_base + mt * 16 + quad * 4 + r;
                    float t = (float)((row & (S_ - 1)) + poff[0]);
                    #pragma unroll
                    for (int nt = 0; nt < 2; ++nt) {
                        int p = nt * 16 + lm;
                        float invf = exp2f(-0.415241012f * (float)p);
                        float ang = t * invf;
                        float sn, cs;
                        sincosf(ang, &sn, &cs);
                        float x1 = acc[mt][nt][r], x2 = acc[mt][nt + 2][r];
                        acc[mt][nt][r]     = x1 * cs - x2 * sn;
                        acc[mt][nt + 2][r] = x2 * cs + x1 * sn;
                    }
                }
        }
        #pragma unroll
        for (int mt = 0; mt < 2; ++mt)
            #pragma unroll
            for (int nt = 0; nt < 4; ++nt)
                #pragma unroll
                for (int r = 0; r < 4; ++r) {
                    int row = row_base + mt * 16 + quad * 4 + r;
                    int col = col_base + nt * 16 + lm;
                    Cb[(size_t)row * ldc + col] = f2bf(acc[mt][nt][r]);
                }
    }
}

// ---------------- Flash attention v13: KVBLK=128, half the barrier rounds --
// Theory: per-round fixed cost (vmcnt drain + barrier + stage addressing)
// dominates (R9 refuted occupancy; m233-style 2-phase overhead). Doubling the
// K-tile to 128 keys amortizes it 2x. LDS 64KB (2 x (16K K + 16K V)) -> 2
// blocks/CU. Race-free 2-buffer schedule: wait vmcnt(0) -> barrier ->
// stage(kt+1, buf^1) -> tile(kt, buf): writers touch buf^1 only after the
// barrier proving all waves finished reading it; loads get a full round in
// flight. Jobs in 128-key rounds: splits C=8..15 (2 halves) + directs C=7..0,
// long first; per-bh totals preserved; merge unchanged.
__global__ __launch_bounds__(256, 2) void attn_kernel13(
    const short* __restrict__ qk,  // [NTOK][1280], K cols pre-roped
    const short* __restrict__ vT,  // [256][NTOK] pi^-1-permuted tokens
    short* __restrict__ attn,      // [NTOK][1024]
    float* __restrict__ Opart,     // [512][64][128]
    float* __restrict__ lpart,     // [512][128]
    const int* __restrict__ poff)
{
    __shared__ short Ks[2][128 * 64];
    __shared__ short Vs[2][64 * 128];

    const int tid = threadIdx.x;
    const int lane = tid & 63, w = tid >> 6;
    const int ql = lane & 31, hi = lane >> 5;

    const int jid = blockIdx.x;
    int bh, C, kt0, kt1, pslot;
    if (jid < 512) {               // split jobs: C = 8..15, two halves
        int i = jid & 255;
        bh = i >> 3;
        int t = i & 7;
        C = 15 - t;                // rounds total = C+1 = 16-t
        int half = jid >> 8;
        int hm = (17 - t) >> 1;
        kt0 = half ? hm : 0;
        kt1 = half ? (16 - t) : hm;
        pslot = (bh * 8 + (7 - t)) * 2 + half;
    } else {                       // direct jobs: C = 7..0 (long first)
        int i = jid - 512;
        bh = i >> 3;
        C = 7 - (i & 7);
        kt0 = 0; kt1 = C + 1; pslot = -1;
    }
    const int h = bh & 15, b = bh >> 4, g = h >> 2;
    const int qwb = C * 128 + w * 32;    // wave q base within batch
    const int qg  = qwb + ql;            // this lane's q row

    const short* qbase = qk + (size_t)b * S_ * NQK;
    const short* kptr  = qbase + 1024 + g * 64;
    const short* vptr  = vT + (size_t)g * 64 * NTOK + (size_t)b * S_;

    // ---- Q as B-operand frags: Qf[ds][e] = Q[d=ds*16+hi*8+e][q=qg] ----
    // RoPE + softmax scale folded in-register (pairs d <-> d+32 = ds <-> ds+2).
    short8 Qf[4];
    {
        const short* qrow = qbase + (size_t)qg * NQK + h * 64;
        short8 raw[4];
        #pragma unroll
        for (int ds = 0; ds < 4; ++ds)
            raw[ds] = *(const short8*)(qrow + ds * 16 + hi * 8);
        const float qs = 0.125f * 1.44269504f;  // 1/sqrt(64)*log2(e)
        float t = (float)(qg + poff[0]);
        #pragma unroll
        for (int ds = 0; ds < 2; ++ds)
            #pragma unroll
            for (int j = 0; j < 8; ++j) {
                int p = ds * 16 + hi * 8 + j;
                float invf = exp2f(-0.415241012f * (float)p);
                float ang = t * invf;
                float sn, cs;
                sincosf(ang, &sn, &cs);
                float x1 = bf2f(raw[ds][j]), x2 = bf2f(raw[ds + 2][j]);
                Qf[ds][j]     = f2bf(qs * (x1 * cs - x2 * sn));
                Qf[ds + 2][j] = f2bf(qs * (x2 * cs + x1 * sn));
            }
    }

    short8 ones8;
    #pragma unroll
    for (int i = 0; i < 8; ++i) ones8[i] = (short)0x3F80;  // bf16 1.0

    floatx16 O0 = {}, O1 = {}, lacc = {};

    // staging: K 128 rows x 128B (8 chunks); V 64 d-rows x 256B (16 chunks).
    // Per-call linear LDS (f*16), swizzled GLOBAL source chunk (rule #21).
    auto stage = [&](int kt2, int buf2) {
        const int k0s = kt2 * 128;
        #pragma unroll
        for (int i = 0; i < 4; ++i) {
            int f = i * 256 + tid;          // 0..1023
            int r  = f >> 3, c = f & 7;     // K row, chunk
            int gc = c ^ (r & 7) ^ ((r >> 3) & 3);
            gload_lds16(kptr + (size_t)(k0s + r) * NQK + gc * 8,
                        (char*)(&Ks[buf2][0]) + f * 16);
            int dv = f >> 4, cv = f & 15;   // V d-row, chunk
            int gv = cv ^ (dv & 7) ^ ((dv >> 3) & 3);   // 3-bit key keeps bit3
            gload_lds16(vptr + (size_t)dv * NTOK + k0s + gv * 8,
                        (char*)(&Vs[buf2][0]) + f * 16);
        }
    };

    // read swizzle key: same for rows ql, ql+32, ql+64, ql+96 (key period 32)
    const int sw2 = (ql & 7) ^ ((ql >> 3) & 3);

    auto tile = [&](int kt, int buf) {
        const int k0 = kt * 128;
        const bool anymask = (k0 + 127 > qwb);
        floatx16 sc[4];
        __builtin_amdgcn_s_setprio(1);
        #pragma unroll
        for (int gk = 0; gk < 4; ++gk) {
            floatx16 s = {};
            #pragma unroll
            for (int ds = 0; ds < 4; ++ds) {
                int ch = ((ds * 2 + hi) ^ sw2) * 8;
                short8 kf = *(const short8*)&Ks[buf][(gk * 32 + ql) * 64 + ch];
                s = __builtin_amdgcn_mfma_f32_32x32x16_bf16(kf, Qf[ds], s, 0, 0, 0);
            }
            sc[gk] = s;
        }
        __builtin_amdgcn_s_setprio(0);
        // exp2 + causal mask, in place
        #pragma unroll
        for (int gk = 0; gk < 4; ++gk)
            #pragma unroll
            for (int r = 0; r < 16; ++r) {
                float v = exp2f(sc[gk][r]);
                if (anymask) {
                    int ko = k0 + gk * 32 + (r >> 2) * 8 + hi * 4 + (r & 3);
                    if (ko > qg) v = 0.f;
                }
                sc[gk][r] = v;
            }
        // PV: per 64-key sub-tile, slot s covers 16 keys; pi-permuted V makes
        // bp = pack(E[2sub][4s..], E[2sub+1][4s..]) feed the MFMA directly.
        __builtin_amdgcn_s_setprio(1);
        #pragma unroll
        for (int sub = 0; sub < 2; ++sub)
            #pragma unroll
            for (int s = 0; s < 4; ++s) {
                uint4 u = { packhi(sc[2*sub][4*s+0], sc[2*sub][4*s+1]),
                            packhi(sc[2*sub][4*s+2], sc[2*sub][4*s+3]),
                            packhi(sc[2*sub+1][4*s+0], sc[2*sub+1][4*s+1]),
                            packhi(sc[2*sub+1][4*s+2], sc[2*sub+1][4*s+3]) };
                short8 bp = __builtin_bit_cast(short8, u);
                int ch = (sub * 8 + ((s * 2 + hi) ^ sw2)) * 8;
                short8 vf0 = *(const short8*)&Vs[buf][ql * 128 + ch];
                short8 vf1 = *(const short8*)&Vs[buf][(32 + ql) * 128 + ch];
                O0   = __builtin_amdgcn_mfma_f32_32x32x16_bf16(vf0,   bp, O0,   0, 0, 0);
                O1   = __builtin_amdgcn_mfma_f32_32x32x16_bf16(vf1,   bp, O1,   0, 0, 0);
                lacc = __builtin_amdgcn_mfma_f32_32x32x16_bf16(ones8, bp, lacc, 0, 0, 0);
            }
        __builtin_amdgcn_s_setprio(0);
    };

    // drain Q loads, then prologue stage
    asm volatile("s_waitcnt vmcnt(0)" ::: "memory");
    stage(kt0, 0);
    for (int kt = kt0; kt < kt1; ++kt) {
        const int buf = (kt - kt0) & 1;
        asm volatile("s_waitcnt vmcnt(0)" ::: "memory");
        asm volatile("s_barrier" ::: "memory");
        if (kt + 1 < kt1) stage(kt + 1, buf ^ 1);
        tile(kt, buf);
    }

    if (pslot >= 0) {
        float* op = Opart + (size_t)pslot * 8192;
        const int qb = w * 32 + ql;
        #pragma unroll
        for (int r = 0; r < 16; ++r) {
            int d = (r & 3) + 8 * (r >> 2) + 4 * hi;
            op[d * 128 + qb]        = O0[r];
            op[(32 + d) * 128 + qb] = O1[r];
        }
        if (hi == 0) lpart[pslot * 128 + qb] = lacc[0];
        return;
    }
    // direct path: every lane has l(q=qg) in lacc[0]; O regs map to
    // d = dblk*32 + q4*8 + hi*4 + (r&3) -> contiguous short4 stores.
    float linv = 1.0f / lacc[0];
    short* ob = attn + (size_t)(b * S_ + qg) * D_ + h * 64;
    #pragma unroll
    for (int q4 = 0; q4 < 4; ++q4) {
        short4 a = { f2bf(O0[q4*4+0] * linv), f2bf(O0[q4*4+1] * linv),
                     f2bf(O0[q4*4+2] * linv), f2bf(O0[q4*4+3] * linv) };
        *(short4*)&ob[q4 * 8 + hi * 4] = a;
        short4 c = { f2bf(O1[q4*4+0] * linv), f2bf(O1[q4*4+1] * linv),
                     f2bf(O1[q4*4+2] * linv), f2bf(O1[q4*4+3] * linv) };
        *(short4*)&ob[32 + q4 * 8 + hi * 4] = c;
    }
}

// ---------------- merge split-k partials: 256 blocks (bh, Cm) --------------
__global__ __launch_bounds__(256) void attn_merge_kernel(
    const float* __restrict__ Opart, const float* __restrict__ lpart,
    short* __restrict__ attn)
{
    __shared__ float Ot[64 * 129];
    __shared__ float ls[128];
    const int bid = blockIdx.x;
    const int bh = bid & 31, Cm = bid >> 5;   // Cm 0..7
    const int h = bh & 15, b = bh >> 4;
    const int C = 8 + Cm;
    const int p0 = (bh * 8 + Cm) * 2;
    const int tid = threadIdx.x;

    if (tid < 128)
        ls[tid] = lpart[p0 * 128 + tid] + lpart[(p0 + 1) * 128 + tid];
    __syncthreads();

    const float* o0 = Opart + (size_t)p0 * 8192;
    const float* o1 = o0 + 8192;
    int d = tid >> 2, q0 = (tid & 3) * 32;
    #pragma unroll
    for (int j = 0; j < 8; ++j) {
        int off = d * 128 + q0 + j * 4;
        float4 a  = *(const float4*)(o0 + off);
        float4 bv = *(const float4*)(o1 + off);
        Ot[d * 129 + q0 + j * 4 + 0] = (a.x + bv.x) / ls[q0 + j * 4 + 0];
        Ot[d * 129 + q0 + j * 4 + 1] = (a.y + bv.y) / ls[q0 + j * 4 + 1];
        Ot[d * 129 + q0 + j * 4 + 2] = (a.z + bv.z) / ls[q0 + j * 4 + 2];
        Ot[d * 129 + q0 + j * 4 + 3] = (a.w + bv.w) / ls[q0 + j * 4 + 3];
    }
    __syncthreads();
    int q = tid & 127, halfd = tid >> 7;
    alignas(16) short vals[32];
    #pragma unroll
    for (int j = 0; j < 32; ++j)
        vals[j] = f2bf(Ot[(halfd * 32 + j) * 129 + q]);
    short* ob = attn + (size_t)(b * S_ + C * 128 + q) * D_ + h * 64 + halfd * 32;
    *(uint4*)&ob[0]  = *(const uint4*)&vals[0];
    *(uint4*)&ob[8]  = *(const uint4*)&vals[8];
    *(uint4*)&ob[16] = *(const uint4*)&vals[16];
    *(uint4*)&ob[24] = *(const uint4*)&vals[24];
}

extern "C" void kernel_launch(void* const* d_in, const int* in_sizes, int n_in,
                              void* d_out, int out_size, void* d_ws, size_t ws_size,
                              hipStream_t stream) {
    const float* x  = (const float*)d_in[0];
    const float* Wq = (const float*)d_in[1];
    const float* Wk = (const float*)d_in[2];
    const float* Wv = (const float*)d_in[3];
    const float* Wo = (const float*)d_in[4];
    const int* poff = (const int*)d_in[5];
    float* out = (float*)d_out;

    short* xb  = (short*)d_ws;                      // [4096][1024]
    short* wt  = xb  + (size_t)NTOK * D_;           // [1536][1024] fused Wqkv^T
    short* woT = wt  + (size_t)NQKV * D_;           // [1024][1024] Wo^T
    short* qkb = woT + (size_t)D_ * D_;             // [4096][1280]
    short* vbT = qkb + (size_t)NTOK * NQK;          // [256][4096] pi^-1-permuted
    short* ab  = vbT + (size_t)(HKV_*DH_) * NTOK;   // [4096][1024]
    float* Opart = (float*)(ab + (size_t)NTOK * D_); // [512][64][128] fp32
    float* lpart = Opart + (size_t)512 * 8192;       // [512][128] fp32

    prep_kernel<<<dim3(4096 + 1024 + 256 + 256 + 1024), 256, 0, stream>>>(
        x, Wq, Wk, Wv, Wo, xb, wt, woT);
    gemm_tn_kernel<2><<<dim3(NQKV / 128, NTOK / 64), 256, 0, stream>>>(
        xb, wt, qkb, nullptr, vbT, NQK, poff);
    attn_kernel13<<<dim3(768), 256, 0, stream>>>(qkb, vbT, ab, Opart, lpart, poff);
    attn_merge_kernel<<<dim3(256), 256, 0, stream>>>(Opart, lpart, ab);
    gemm_tn_kernel<1><<<dim3(D_ / 128, NTOK / 64), 256, 0, stream>>>(
        ab, woT, nullptr, out, nullptr, D_, poff);
}

// Round 12
// 172.794 us; speedup vs baseline: 1.1444x; 1.1444x over previous
//
#include <hip/hip_runtime.h>
#include <hip/hip_bf16.h>
#include <math.h>

#define B_ 2
#define S_ 2048
#define D_ 1024
#define H_ 16
#define HKV_ 4
#define DH_ 64
#define NTOK (B_*S_)     // 4096
#define NQK 1280         // q(1024) + k(256) fused cols
#define NQKV 1536        // + v

typedef __attribute__((ext_vector_type(8))) short short8;
typedef __attribute__((ext_vector_type(4))) float floatx4;
typedef __attribute__((ext_vector_type(16))) float floatx16;

__device__ __forceinline__ short f2bf(float f) {
    union { __hip_bfloat16 h; short s; } u;
    u.h = __float2bfloat16(f);
    return u.s;
}
__device__ __forceinline__ float bf2f(short s) {
    union { __hip_bfloat16 h; short t; } u;
    u.t = s;
    return __bfloat162float(u.h);
}
__device__ __forceinline__ unsigned fbits(float f) {
    union { float f; unsigned u; } u; u.f = f; return u.u;
}
// pack hi16(a) | hi16(b)<<16 in ONE v_perm_b32 (RTZ bf16 truncation)
__device__ __forceinline__ unsigned packhi(float a, float b) {
    return __builtin_amdgcn_perm(fbits(b), fbits(a), 0x07060302u);
}

__device__ __forceinline__ void gload_lds16(const void* g, void* l) {
    __builtin_amdgcn_global_load_lds(
        (const __attribute__((address_space(1))) void*)g,
        (__attribute__((address_space(3))) void*)l, 16, 0, 0);
}

// ---------------- fused prep: x->bf16 convert + 4 weight transposes --------
__global__ __launch_bounds__(256) void prep_kernel(
    const float* __restrict__ x,  const float* __restrict__ Wq,
    const float* __restrict__ Wk, const float* __restrict__ Wv,
    const float* __restrict__ Wo,
    short* __restrict__ xb, short* __restrict__ wt, short* __restrict__ woT)
{
    int bid = blockIdx.x;
    if (bid < 4096) {
        int i = bid * 256 + threadIdx.x;
        float4 v = ((const float4*)x)[i];
        short4 o = { f2bf(v.x), f2bf(v.y), f2bf(v.z), f2bf(v.w) };
        ((short4*)xb)[i] = o;
        return;
    }
    bid -= 4096;
    const float* src; short* dst; int N;
    if (bid < 1024)      { src = Wq; dst = wt;                        N = 1024; }
    else if (bid < 1280) { bid -= 1024; src = Wk; dst = wt + (size_t)1024 * 1024; N = 256; }
    else if (bid < 1536) { bid -= 1280; src = Wv; dst = wt + (size_t)1280 * 1024; N = 256; }
    else                 { bid -= 1536; src = Wo; dst = woT;          N = 1024; }
    __shared__ float t[32][33];
    int tiles_n = N / 32;
    int n0 = (bid % tiles_n) * 32, k0 = (bid / tiles_n) * 32;
    int tx = threadIdx.x & 31, ty = threadIdx.x >> 5;
    #pragma unroll
    for (int i = 0; i < 4; ++i)
        t[ty + 8 * i][tx] = src[(size_t)(k0 + ty + 8 * i) * N + n0 + tx];
    __syncthreads();
    #pragma unroll
    for (int i = 0; i < 4; ++i)
        dst[(size_t)(n0 + ty + 8 * i) * 1024 + k0 + tx] = f2bf(t[tx][ty + 8 * i]);
}

// ---------------- GEMM: C[M,N] = A[M,1024] @ Bt[N,1024]^T (bf16 MFMA) -------
// 64x128 tile, BK=32, 256 thr = 4 waves as 2x2 -> wave 32 rows x 64 cols
// (acc 2x4). 3-stage LDS ring, counted vmcnt(3). Both-sides chunk swizzle
// (c ^ ((r>>1)&3)) keeps ds_read 2-way (free).
// T1 XCD swizzle: consecutive jobs (same A-row panel) pinned to one XCD ->
// per-XCD working set ~= A 1MB + B 3MB ~= L2 size. Grids divisible by 8.
// MODE 2: K region fuses RoPE in-register in the epilogue; V region stores
// transposed with pi^-1 token permutation (attn PV B-operand pure-register).
template<int MODE>
__global__ __launch_bounds__(256, 4) void gemm_tn_kernel(
    const short* __restrict__ A, const short* __restrict__ Bt,
    short* __restrict__ Cb, float* __restrict__ Cf, short* __restrict__ Ct,
    int ldc, const int* __restrict__ poff)
{
    __shared__ short As[3][64 * 32];
    __shared__ short Bs[3][128 * 32];
    const int K = 1024;
    const int tid = threadIdx.x;

    // XCD-aware job remap (bijective: nwg % 8 == 0 for both grids)
    const int id  = blockIdx.y * gridDim.x + blockIdx.x;
    const int nwg = gridDim.x * gridDim.y;
    const int per = nwg >> 3;
    const int job = (id & 7) * per + (id >> 3);
    const int bm0 = (job / gridDim.x) * 64;
    const int bn0 = (job % gridDim.x) * 128;

    const int lane = tid & 63, w = tid >> 6;
    const int wm = (w >> 1) * 32, wn = (w & 1) * 64;
    const int lm = lane & 15, quad = lane >> 4;

    floatx4 acc[2][4] = {};

    const int r0  = tid >> 2;                       // staged row 0..63
    const int kb0 = (((tid & 3) ^ ((r0 >> 1) & 3)) ) * 16;  // swizzled src chunk (bytes)

    auto stage = [&](int kt, int buf) {
        const char* gaA = (const char*)A  + ((size_t)(bm0 + r0) * K + kt) * 2 + kb0;
        const char* gaB = (const char*)Bt + ((size_t)(bn0 + r0) * K + kt) * 2 + kb0;
        gload_lds16(gaA,                      (char*)As[buf] + tid * 16);
        gload_lds16(gaB,                      (char*)Bs[buf] + tid * 16);
        gload_lds16(gaB + (size_t)64 * K * 2, (char*)Bs[buf] + 4096 + tid * 16);
    };

    const int swr = (lm >> 1) & 3;

    stage(0, 0);
    stage(32, 1);
    for (int kt = 0; kt < K; kt += 32) {
        const int it = kt >> 5;
        const int buf = it % 3;
        if (it < (K / 32) - 1) asm volatile("s_waitcnt vmcnt(3)" ::: "memory");
        else                   asm volatile("s_waitcnt vmcnt(0)" ::: "memory");
        asm volatile("s_barrier" ::: "memory");
        if (kt + 64 < K) stage(kt + 64, (it + 2) % 3);

        short8 af[2], bfr[4];
        #pragma unroll
        for (int mt = 0; mt < 2; ++mt)
            af[mt] = *(const short8*)&As[buf][(wm + mt * 16 + lm) * 32 + ((quad ^ swr) * 8)];
        #pragma unroll
        for (int nt = 0; nt < 4; ++nt)
            bfr[nt] = *(const short8*)&Bs[buf][(wn + nt * 16 + lm) * 32 + ((quad ^ swr) * 8)];
        #pragma unroll
        for (int mt = 0; mt < 2; ++mt)
            #pragma unroll
            for (int nt = 0; nt < 4; ++nt)
                acc[mt][nt] = __builtin_amdgcn_mfma_f32_16x16x32_bf16(
                    af[mt], bfr[nt], acc[mt][nt], 0, 0, 0);
    }

    const int col_base = bn0 + wn;
    const int row_base = bm0 + wm;
    if (MODE == 2 && bn0 >= NQK) {  // V tiles -> transposed, pi^-1-permuted store
        #pragma unroll
        for (int mt = 0; mt < 2; ++mt)
            #pragma unroll
            for (int nt = 0; nt < 4; ++nt) {
                int vcol = col_base + nt * 16 + lm - NQK;
                int row0 = row_base + mt * 16 + quad * 4;
                // pi^-1 within 64: bit2 = old bit5, bits3..5 = old bits2..4
                int prow = (row0 & ~60) | ((row0 & 32) >> 3) | ((row0 & 0x1C) << 1);
                short4 o = { f2bf(acc[mt][nt][0]), f2bf(acc[mt][nt][1]),
                             f2bf(acc[mt][nt][2]), f2bf(acc[mt][nt][3]) };
                *(short4*)&Ct[(size_t)vcol * NTOK + prow] = o;
            }
    } else if (MODE == 1) {
        #pragma unroll
        for (int mt = 0; mt < 2; ++mt)
            #pragma unroll
            for (int nt = 0; nt < 4; ++nt)
                #pragma unroll
                for (int r = 0; r < 4; ++r) {
                    int row = row_base + mt * 16 + quad * 4 + r;
                    int col = col_base + nt * 16 + lm;
                    Cf[(size_t)row * ldc + col] = acc[mt][nt][r];
                }
    } else {
        if (MODE == 2 && bn0 >= 1024) {
            // K region: fused RoPE. p = nt*16+lm (<32) pairs with p+32 = nt+2.
            #pragma unroll
            for (int mt = 0; mt < 2; ++mt)
                #pragma unroll
                for (int r = 0; r < 4; ++r) {
                    int row = row_base + mt * 16 + quad * 4 + r;
                    float t = (float)((row & (S_ - 1)) + poff[0]);
                    #pragma unroll
                    for (int nt = 0; nt < 2; ++nt) {
                        int p = nt * 16 + lm;
                        float invf = exp2f(-0.415241012f * (float)p);
                        float ang = t * invf;
                        float sn, cs;
                        __sincosf(ang, &sn, &cs);
                        float x1 = acc[mt][nt][r], x2 = acc[mt][nt + 2][r];
                        acc[mt][nt][r]     = x1 * cs - x2 * sn;
                        acc[mt][nt + 2][r] = x2 * cs + x1 * sn;
                    }
                }
        }
        #pragma unroll
        for (int mt = 0; mt < 2; ++mt)
            #pragma unroll
            for (int nt = 0; nt < 4; ++nt)
                #pragma unroll
                for (int r = 0; r < 4; ++r) {
                    int row = row_base + mt * 16 + quad * 4 + r;
                    int col = col_base + nt * 16 + lm;
                    Cb[(size_t)row * ldc + col] = f2bf(acc[mt][nt][r]);
                }
    }
}

// ---------------- Flash attention v10: 32x32 MFMA, balanced + pipelined ----
// Grid = 3 banks of 256; blocks {i, i+256, i+512} form a triple
// {split(C=15-t,h0), split(C=15-t,h1), direct(C=t)} summing to exactly 34
// tiles -> every CU gets 34 tiles (stride-256 round-robin co-location).
// LDS: 3-buffer ring, counted vmcnt(4) keeps one stage in flight across the
// barrier. Swizzle key f(r) = (r&7)^((r>>3)&3) varies within lane-mod-8
// phase groups -> conflict-free ds_read_b128.
__global__ __launch_bounds__(256, 3) void attn_kernel10(
    const short* __restrict__ qk,  // [NTOK][1280], K cols pre-roped
    const short* __restrict__ vT,  // [256][NTOK] pi^-1-permuted tokens
    short* __restrict__ attn,      // [NTOK][1024]
    float* __restrict__ Opart,     // [512][64][128]
    float* __restrict__ lpart,     // [512][128]
    const int* __restrict__ poff)
{
    __shared__ short Ks[3][64 * 64];
    __shared__ short Vs[3][64 * 64];

    const int tid = threadIdx.x;
    const int lane = tid & 63, w = tid >> 6;
    const int ql = lane & 31, hi = lane >> 5;

    const int jid = blockIdx.x;
    int bh, C, kt0, kt1, pslot;
    if (jid < 512) {               // split jobs: C = 8..15, two halves
        int i = jid & 255;
        bh = i >> 3;
        int t = i & 7;
        C = 15 - t;
        int half = jid >> 8;       // bank 0 -> half 0, bank 1 -> half 1
        kt0 = half ? (C + 1) : 0;
        kt1 = half ? (2 * C + 2) : (C + 1);
        pslot = (bh * 8 + (7 - t)) * 2 + half;
    } else {                       // direct jobs: C = 0..7
        int i = jid - 512;
        bh = i >> 3;
        C = i & 7;
        kt0 = 0; kt1 = 2 * C + 2; pslot = -1;
    }
    const int h = bh & 15, b = bh >> 4, g = h >> 2;
    const int qwb = C * 128 + w * 32;    // wave q base within batch
    const int qg  = qwb + ql;            // this lane's q row

    const short* qbase = qk + (size_t)b * S_ * NQK;
    const short* kptr  = qbase + 1024 + g * 64;
    const short* vptr  = vT + (size_t)g * 64 * NTOK + (size_t)b * S_;

    // ---- Q as B-operand frags: Qf[ds][e] = Q[d=ds*16+hi*8+e][q=qg] ----
    // RoPE + softmax scale folded in-register (pairs d <-> d+32 = ds <-> ds+2).
    short8 Qf[4];
    {
        const short* qrow = qbase + (size_t)qg * NQK + h * 64;
        short8 raw[4];
        #pragma unroll
        for (int ds = 0; ds < 4; ++ds)
            raw[ds] = *(const short8*)(qrow + ds * 16 + hi * 8);
        const float qs = 0.125f * 1.44269504f;  // 1/sqrt(64)*log2(e)
        float t = (float)(qg + poff[0]);
        #pragma unroll
        for (int ds = 0; ds < 2; ++ds)
            #pragma unroll
            for (int j = 0; j < 8; ++j) {
                int p = ds * 16 + hi * 8 + j;
                float invf = exp2f(-0.415241012f * (float)p);
                float ang = t * invf;
                float sn, cs;
                __sincosf(ang, &sn, &cs);
                float x1 = bf2f(raw[ds][j]), x2 = bf2f(raw[ds + 2][j]);
                Qf[ds][j]     = f2bf(qs * (x1 * cs - x2 * sn));
                Qf[ds + 2][j] = f2bf(qs * (x2 * cs + x1 * sn));
            }
    }

    short8 ones8;
    #pragma unroll
    for (int i = 0; i < 8; ++i) ones8[i] = (short)0x3F80;  // bf16 1.0

    floatx16 O0 = {}, O1 = {}, lacc = {};

    const int sr = tid >> 3;     // 0..31
    const int cc = tid & 7;

    auto stage = [&](int kt2, int buf2) {
        const int k0s = kt2 * 64;
        #pragma unroll
        for (int i = 0; i < 2; ++i) {
            int r  = i * 32 + sr;
            int gc = cc ^ (r & 7) ^ ((r >> 3) & 3);
            gload_lds16(kptr + (size_t)(k0s + r) * NQK + gc * 8,
                        (char*)(&Ks[buf2][0]) + (i * 256 + tid) * 16);
            gload_lds16(vptr + (size_t)r * NTOK + k0s + gc * 8,
                        (char*)(&Vs[buf2][0]) + (i * 256 + tid) * 16);
        }
    };

    // swizzle key: same for rows ql and ql+32 (f(r)=f(r+32))
    const int sw2 = (ql & 7) ^ ((ql >> 3) & 3);

    auto tile = [&](int kt, int buf) {
        const int k0 = kt * 64;
        if (k0 > qwb + 31) return;               // wave fully masked
        const bool anymask = (k0 + 63 > qwb);
        floatx16 s0 = {}, s1 = {};
        __builtin_amdgcn_s_setprio(1);
        #pragma unroll
        for (int ds = 0; ds < 4; ++ds) {
            int ch = ((ds * 2 + hi) ^ sw2) * 8;
            short8 kf0 = *(const short8*)&Ks[buf][ql * 64 + ch];
            short8 kf1 = *(const short8*)&Ks[buf][(32 + ql) * 64 + ch];
            s0 = __builtin_amdgcn_mfma_f32_32x32x16_bf16(kf0, Qf[ds], s0, 0, 0, 0);
            s1 = __builtin_amdgcn_mfma_f32_32x32x16_bf16(kf1, Qf[ds], s1, 0, 0, 0);
        }
        __builtin_amdgcn_s_setprio(0);
        // exp2 + causal mask, in place
        #pragma unroll
        for (int r = 0; r < 16; ++r) {
            float v0 = exp2f(s0[r]);
            float v1 = exp2f(s1[r]);
            if (anymask) {
                int ko = k0 + (r >> 2) * 8 + hi * 4 + (r & 3);
                if (ko > qg)      v0 = 0.f;
                if (ko + 32 > qg) v1 = 0.f;
            }
            s0[r] = v0; s1[r] = v1;
        }
        // PV: B-frag for step s = pack(E0[4s..4s+3], E1[4s..4s+3]) (pi-match)
        __builtin_amdgcn_s_setprio(1);
        #pragma unroll
        for (int s = 0; s < 4; ++s) {
            uint4 u = { packhi(s0[4*s+0], s0[4*s+1]), packhi(s0[4*s+2], s0[4*s+3]),
                        packhi(s1[4*s+0], s1[4*s+1]), packhi(s1[4*s+2], s1[4*s+3]) };
            short8 bp = __builtin_bit_cast(short8, u);
            int ch = ((s * 2 + hi) ^ sw2) * 8;
            short8 vf0 = *(const short8*)&Vs[buf][ql * 64 + ch];
            short8 vf1 = *(const short8*)&Vs[buf][(32 + ql) * 64 + ch];
            O0   = __builtin_amdgcn_mfma_f32_32x32x16_bf16(vf0,   bp, O0,   0, 0, 0);
            O1   = __builtin_amdgcn_mfma_f32_32x32x16_bf16(vf1,   bp, O1,   0, 0, 0);
            lacc = __builtin_amdgcn_mfma_f32_32x32x16_bf16(ones8, bp, lacc, 0, 0, 0);
        }
        __builtin_amdgcn_s_setprio(0);
    };

    // drain Q loads so counted vmcnt below sees only stage loads
    asm volatile("s_waitcnt vmcnt(0)" ::: "memory");
    stage(kt0, 0);
    if (kt0 + 1 < kt1) stage(kt0 + 1, 1);
    for (int kt = kt0; kt < kt1; ++kt) {
        const int it = kt - kt0;
        const int buf = it % 3;
        if (kt + 1 < kt1) asm volatile("s_waitcnt vmcnt(4)" ::: "memory");
        else              asm volatile("s_waitcnt vmcnt(0)" ::: "memory");
        asm volatile("s_barrier" ::: "memory");
        if (kt + 2 < kt1) stage(kt + 2, (it + 2) % 3);
        tile(kt, buf);
    }

    if (pslot >= 0) {
        float* op = Opart + (size_t)pslot * 8192;
        const int qb = w * 32 + ql;
        #pragma unroll
        for (int r = 0; r < 16; ++r) {
            int d = (r & 3) + 8 * (r >> 2) + 4 * hi;
            op[d * 128 + qb]        = O0[r];
            op[(32 + d) * 128 + qb] = O1[r];
        }
        if (hi == 0) lpart[pslot * 128 + qb] = lacc[0];
        return;
    }
    // direct path: every lane has l(q=qg) in lacc[0]; O regs map to
    // d = dblk*32 + q4*8 + hi*4 + (r&3) -> contiguous short4 stores.
    float linv = 1.0f / lacc[0];
    short* ob = attn + (size_t)(b * S_ + qg) * D_ + h * 64;
    #pragma unroll
    for (int q4 = 0; q4 < 4; ++q4) {
        short4 a = { f2bf(O0[q4*4+0] * linv), f2bf(O0[q4*4+1] * linv),
                     f2bf(O0[q4*4+2] * linv), f2bf(O0[q4*4+3] * linv) };
        *(short4*)&ob[q4 * 8 + hi * 4] = a;
        short4 c = { f2bf(O1[q4*4+0] * linv), f2bf(O1[q4*4+1] * linv),
                     f2bf(O1[q4*4+2] * linv), f2bf(O1[q4*4+3] * linv) };
        *(short4*)&ob[32 + q4 * 8 + hi * 4] = c;
    }
}

// ---------------- merge split-k partials: 256 blocks (bh, Cm) --------------
__global__ __launch_bounds__(256) void attn_merge_kernel(
    const float* __restrict__ Opart, const float* __restrict__ lpart,
    short* __restrict__ attn)
{
    __shared__ float Ot[64 * 129];
    __shared__ float ls[128];
    const int bid = blockIdx.x;
    const int bh = bid & 31, Cm = bid >> 5;   // Cm 0..7
    const int h = bh & 15, b = bh >> 4;
    const int C = 8 + Cm;
    const int p0 = (bh * 8 + Cm) * 2;
    const int tid = threadIdx.x;

    if (tid < 128)
        ls[tid] = lpart[p0 * 128 + tid] + lpart[(p0 + 1) * 128 + tid];
    __syncthreads();

    const float* o0 = Opart + (size_t)p0 * 8192;
    const float* o1 = o0 + 8192;
    int d = tid >> 2, q0 = (tid & 3) * 32;
    #pragma unroll
    for (int j = 0; j < 8; ++j) {
        int off = d * 128 + q0 + j * 4;
        float4 a  = *(const float4*)(o0 + off);
        float4 bv = *(const float4*)(o1 + off);
        Ot[d * 129 + q0 + j * 4 + 0] = (a.x + bv.x) / ls[q0 + j * 4 + 0];
        Ot[d * 129 + q0 + j * 4 + 1] = (a.y + bv.y) / ls[q0 + j * 4 + 1];
        Ot[d * 129 + q0 + j * 4 + 2] = (a.z + bv.z) / ls[q0 + j * 4 + 2];
        Ot[d * 129 + q0 + j * 4 + 3] = (a.w + bv.w) / ls[q0 + j * 4 + 3];
    }
    __syncthreads();
    int q = tid & 127, halfd = tid >> 7;
    alignas(16) short vals[32];
    #pragma unroll
    for (int j = 0; j < 32; ++j)
        vals[j] = f2bf(Ot[(halfd * 32 + j) * 129 + q]);
    short* ob = attn + (size_t)(b * S_ + C * 128 + q) * D_ + h * 64 + halfd * 32;
    *(uint4*)&ob[0]  = *(const uint4*)&vals[0];
    *(uint4*)&ob[8]  = *(const uint4*)&vals[8];
    *(uint4*)&ob[16] = *(const uint4*)&vals[16];
    *(uint4*)&ob[24] = *(const uint4*)&vals[24];
}

extern "C" void kernel_launch(void* const* d_in, const int* in_sizes, int n_in,
                              void* d_out, int out_size, void* d_ws, size_t ws_size,
                              hipStream_t stream) {
    const float* x  = (const float*)d_in[0];
    const float* Wq = (const float*)d_in[1];
    const float* Wk = (const float*)d_in[2];
    const float* Wv = (const float*)d_in[3];
    const float* Wo = (const float*)d_in[4];
    const int* poff = (const int*)d_in[5];
    float* out = (float*)d_out;

    short* xb  = (short*)d_ws;                      // [4096][1024]
    short* wt  = xb  + (size_t)NTOK * D_;           // [1536][1024] fused Wqkv^T
    short* woT = wt  + (size_t)NQKV * D_;           // [1024][1024] Wo^T
    short* qkb = woT + (size_t)D_ * D_;             // [4096][1280]
    short* vbT = qkb + (size_t)NTOK * NQK;          // [256][4096] pi^-1-permuted
    short* ab  = vbT + (size_t)(HKV_*DH_) * NTOK;   // [4096][1024]
    float* Opart = (float*)(ab + (size_t)NTOK * D_); // [512][64][128] fp32
    float* lpart = Opart + (size_t)512 * 8192;       // [512][128] fp32

    prep_kernel<<<dim3(4096 + 1024 + 256 + 256 + 1024), 256, 0, stream>>>(
        x, Wq, Wk, Wv, Wo, xb, wt, woT);
    gemm_tn_kernel<2><<<dim3(NQKV / 128, NTOK / 64), 256, 0, stream>>>(
        xb, wt, qkb, nullptr, vbT, NQK, poff);
    attn_kernel10<<<dim3(768), 256, 0, stream>>>(qkb, vbT, ab, Opart, lpart, poff);
    attn_merge_kernel<<<dim3(256), 256, 0, stream>>>(Opart, lpart, ab);
    gemm_tn_kernel<1><<<dim3(D_ / 128, NTOK / 64), 256, 0, stream>>>(
        ab, woT, nullptr, out, nullptr, D_, poff);
}

// Round 13
// 172.388 us; speedup vs baseline: 1.1471x; 1.0024x over previous
//
#include <hip/hip_runtime.h>
#include <hip/hip_bf16.h>
#include <math.h>

#define B_ 2
#define S_ 2048
#define D_ 1024
#define H_ 16
#define HKV_ 4
#define DH_ 64
#define NTOK (B_*S_)     // 4096
#define NQK 1280         // q(1024) + k(256) fused cols
#define NQKV 1536        // + v

typedef __attribute__((ext_vector_type(8))) short short8;
typedef __attribute__((ext_vector_type(4))) float floatx4;
typedef __attribute__((ext_vector_type(16))) float floatx16;

__device__ __forceinline__ short f2bf(float f) {
    union { __hip_bfloat16 h; short s; } u;
    u.h = __float2bfloat16(f);
    return u.s;
}
__device__ __forceinline__ float bf2f(short s) {
    union { __hip_bfloat16 h; short t; } u;
    u.t = s;
    return __bfloat162float(u.h);
}
__device__ __forceinline__ unsigned fbits(float f) {
    union { float f; unsigned u; } u; u.f = f; return u.u;
}
// pack hi16(a) | hi16(b)<<16 in ONE v_perm_b32 (RTZ bf16 truncation)
__device__ __forceinline__ unsigned packhi(float a, float b) {
    return __builtin_amdgcn_perm(fbits(b), fbits(a), 0x07060302u);
}

__device__ __forceinline__ void gload_lds16(const void* g, void* l) {
    __builtin_amdgcn_global_load_lds(
        (const __attribute__((address_space(1))) void*)g,
        (__attribute__((address_space(3))) void*)l, 16, 0, 0);
}

// ---------------- fused prep: x->bf16 convert + 4 weight transposes --------
__global__ __launch_bounds__(256) void prep_kernel(
    const float* __restrict__ x,  const float* __restrict__ Wq,
    const float* __restrict__ Wk, const float* __restrict__ Wv,
    const float* __restrict__ Wo,
    short* __restrict__ xb, short* __restrict__ wt, short* __restrict__ woT)
{
    int bid = blockIdx.x;
    if (bid < 4096) {
        int i = bid * 256 + threadIdx.x;
        float4 v = ((const float4*)x)[i];
        short4 o = { f2bf(v.x), f2bf(v.y), f2bf(v.z), f2bf(v.w) };
        ((short4*)xb)[i] = o;
        return;
    }
    bid -= 4096;
    const float* src; short* dst; int N;
    if (bid < 1024)      { src = Wq; dst = wt;                        N = 1024; }
    else if (bid < 1280) { bid -= 1024; src = Wk; dst = wt + (size_t)1024 * 1024; N = 256; }
    else if (bid < 1536) { bid -= 1280; src = Wv; dst = wt + (size_t)1280 * 1024; N = 256; }
    else                 { bid -= 1536; src = Wo; dst = woT;          N = 1024; }
    __shared__ float t[32][33];
    int tiles_n = N / 32;
    int n0 = (bid % tiles_n) * 32, k0 = (bid / tiles_n) * 32;
    int tx = threadIdx.x & 31, ty = threadIdx.x >> 5;
    #pragma unroll
    for (int i = 0; i < 4; ++i)
        t[ty + 8 * i][tx] = src[(size_t)(k0 + ty + 8 * i) * N + n0 + tx];
    __syncthreads();
    #pragma unroll
    for (int i = 0; i < 4; ++i)
        dst[(size_t)(n0 + ty + 8 * i) * 1024 + k0 + tx] = f2bf(t[tx][ty + 8 * i]);
}

// ---------------- GEMM: C[M,N] = A[M,1024] @ Bt[N,1024]^T (bf16 MFMA) -------
// 64x128 tile, BK=32, 256 thr = 4 waves as 2x2 -> wave 32 rows x 64 cols
// (acc 2x4). 3-stage LDS ring, counted vmcnt(3). Both-sides chunk swizzle
// (c ^ ((r>>1)&3)) keeps ds_read 2-way (free).
// T1 XCD swizzle: consecutive jobs (same A-row panel) pinned to one XCD ->
// per-XCD working set ~= A 1MB + B 3MB ~= L2 size. Grids divisible by 8.
// MODE 2: K region fuses RoPE in-register in the epilogue; V region stores
// transposed with pi^-1 token permutation (attn PV B-operand pure-register).
template<int MODE>
__global__ __launch_bounds__(256, 4) void gemm_tn_kernel(
    const short* __restrict__ A, const short* __restrict__ Bt,
    short* __restrict__ Cb, float* __restrict__ Cf, short* __restrict__ Ct,
    int ldc, const int* __restrict__ poff)
{
    __shared__ short As[3][64 * 32];
    __shared__ short Bs[3][128 * 32];
    const int K = 1024;
    const int tid = threadIdx.x;

    // XCD-aware job remap (bijective: nwg % 8 == 0 for both grids)
    const int id  = blockIdx.y * gridDim.x + blockIdx.x;
    const int nwg = gridDim.x * gridDim.y;
    const int per = nwg >> 3;
    const int job = (id & 7) * per + (id >> 3);
    const int bm0 = (job / gridDim.x) * 64;
    const int bn0 = (job % gridDim.x) * 128;

    const int lane = tid & 63, w = tid >> 6;
    const int wm = (w >> 1) * 32, wn = (w & 1) * 64;
    const int lm = lane & 15, quad = lane >> 4;

    floatx4 acc[2][4] = {};

    const int r0  = tid >> 2;                       // staged row 0..63
    const int kb0 = (((tid & 3) ^ ((r0 >> 1) & 3)) ) * 16;  // swizzled src chunk (bytes)

    auto stage = [&](int kt, int buf) {
        const char* gaA = (const char*)A  + ((size_t)(bm0 + r0) * K + kt) * 2 + kb0;
        const char* gaB = (const char*)Bt + ((size_t)(bn0 + r0) * K + kt) * 2 + kb0;
        gload_lds16(gaA,                      (char*)As[buf] + tid * 16);
        gload_lds16(gaB,                      (char*)Bs[buf] + tid * 16);
        gload_lds16(gaB + (size_t)64 * K * 2, (char*)Bs[buf] + 4096 + tid * 16);
    };

    const int swr = (lm >> 1) & 3;

    stage(0, 0);
    stage(32, 1);
    for (int kt = 0; kt < K; kt += 32) {
        const int it = kt >> 5;
        const int buf = it % 3;
        if (it < (K / 32) - 1) asm volatile("s_waitcnt vmcnt(3)" ::: "memory");
        else                   asm volatile("s_waitcnt vmcnt(0)" ::: "memory");
        asm volatile("s_barrier" ::: "memory");
        if (kt + 64 < K) stage(kt + 64, (it + 2) % 3);

        short8 af[2], bfr[4];
        #pragma unroll
        for (int mt = 0; mt < 2; ++mt)
            af[mt] = *(const short8*)&As[buf][(wm + mt * 16 + lm) * 32 + ((quad ^ swr) * 8)];
        #pragma unroll
        for (int nt = 0; nt < 4; ++nt)
            bfr[nt] = *(const short8*)&Bs[buf][(wn + nt * 16 + lm) * 32 + ((quad ^ swr) * 8)];
        #pragma unroll
        for (int mt = 0; mt < 2; ++mt)
            #pragma unroll
            for (int nt = 0; nt < 4; ++nt)
                acc[mt][nt] = __builtin_amdgcn_mfma_f32_16x16x32_bf16(
                    af[mt], bfr[nt], acc[mt][nt], 0, 0, 0);
    }

    const int col_base = bn0 + wn;
    const int row_base = bm0 + wm;
    if (MODE == 2 && bn0 >= NQK) {  // V tiles -> transposed, pi^-1-permuted store
        #pragma unroll
        for (int mt = 0; mt < 2; ++mt)
            #pragma unroll
            for (int nt = 0; nt < 4; ++nt) {
                int vcol = col_base + nt * 16 + lm - NQK;
                int row0 = row_base + mt * 16 + quad * 4;
                // pi^-1 within 64: bit2 = old bit5, bits3..5 = old bits2..4
                int prow = (row0 & ~60) | ((row0 & 32) >> 3) | ((row0 & 0x1C) << 1);
                short4 o = { f2bf(acc[mt][nt][0]), f2bf(acc[mt][nt][1]),
                             f2bf(acc[mt][nt][2]), f2bf(acc[mt][nt][3]) };
                *(short4*)&Ct[(size_t)vcol * NTOK + prow] = o;
            }
    } else if (MODE == 1) {
        #pragma unroll
        for (int mt = 0; mt < 2; ++mt)
            #pragma unroll
            for (int nt = 0; nt < 4; ++nt)
                #pragma unroll
                for (int r = 0; r < 4; ++r) {
                    int row = row_base + mt * 16 + quad * 4 + r;
                    int col = col_base + nt * 16 + lm;
                    Cf[(size_t)row * ldc + col] = acc[mt][nt][r];
                }
    } else {
        if (MODE == 2 && bn0 >= 1024) {
            // K region: fused RoPE. p = nt*16+lm (<32) pairs with p+32 = nt+2.
            #pragma unroll
            for (int mt = 0; mt < 2; ++mt)
                #pragma unroll
                for (int r = 0; r < 4; ++r) {
                    int row = row_base + mt * 16 + quad * 4 + r;
                    float t = (float)((row & (S_ - 1)) + poff[0]);
                    #pragma unroll
                    for (int nt = 0; nt < 2; ++nt) {
                        int p = nt * 16 + lm;
                        float invf = exp2f(-0.415241012f * (float)p);
                        float ang = t * invf;
                        float sn, cs;
                        __sincosf(ang, &sn, &cs);
                        float x1 = acc[mt][nt][r], x2 = acc[mt][nt + 2][r];
                        acc[mt][nt][r]     = x1 * cs - x2 * sn;
                        acc[mt][nt + 2][r] = x2 * cs + x1 * sn;
                    }
                }
        }
        #pragma unroll
        for (int mt = 0; mt < 2; ++mt)
            #pragma unroll
            for (int nt = 0; nt < 4; ++nt)
                #pragma unroll
                for (int r = 0; r < 4; ++r) {
                    int row = row_base + mt * 16 + quad * 4 + r;
                    int col = col_base + nt * 16 + lm;
                    Cb[(size_t)row * ldc + col] = f2bf(acc[mt][nt][r]);
                }
    }
}

// ---------------- Flash attention v14: v10 + XCD-local (b,h) mapping -------
// Physical block jid -> XCD jid%8 (round-robin). Remap so XCD x owns
// bh === x (mod 8): x=jid&7, m=jid>>3; bh=x+8*(m&3); rest=m>>2;
// role=rest>>3 (0,1=split halves, 2=direct); t=rest&7.
// Per-XCD KV working set: 4 bh x 512KB = 2MB (fits 4MB L2); triple balance
// preserved: blocks {jid, jid+256, jid+512} share (bh,t) with roles
// {half0, half1, direct} -> 34 tiles per CU exactly (as v10).
__global__ __launch_bounds__(256, 3) void attn_kernel14(
    const short* __restrict__ qk,  // [NTOK][1280], K cols pre-roped
    const short* __restrict__ vT,  // [256][NTOK] pi^-1-permuted tokens
    short* __restrict__ attn,      // [NTOK][1024]
    float* __restrict__ Opart,     // [512][64][128]
    float* __restrict__ lpart,     // [512][128]
    const int* __restrict__ poff)
{
    __shared__ short Ks[3][64 * 64];
    __shared__ short Vs[3][64 * 64];

    const int tid = threadIdx.x;
    const int lane = tid & 63, w = tid >> 6;
    const int ql = lane & 31, hi = lane >> 5;

    const int jid = blockIdx.x;
    const int x = jid & 7, m = jid >> 3;
    const int bh = x + 8 * (m & 3);
    const int rest = m >> 2;            // 0..23
    const int role = rest >> 3;         // 0,1 = split halves; 2 = direct
    const int t = rest & 7;
    int C, kt0, kt1, pslot;
    if (role < 2) {                     // split jobs: C = 8..15
        C = 15 - t;
        kt0 = role ? (C + 1) : 0;
        kt1 = role ? (2 * C + 2) : (C + 1);
        pslot = (bh * 8 + (7 - t)) * 2 + role;
    } else {                            // direct jobs: C = 0..7
        C = t;
        kt0 = 0; kt1 = 2 * C + 2; pslot = -1;
    }
    const int h = bh & 15, b = bh >> 4, g = h >> 2;
    const int qwb = C * 128 + w * 32;    // wave q base within batch
    const int qg  = qwb + ql;            // this lane's q row

    const short* qbase = qk + (size_t)b * S_ * NQK;
    const short* kptr  = qbase + 1024 + g * 64;
    const short* vptr  = vT + (size_t)g * 64 * NTOK + (size_t)b * S_;

    // ---- Q as B-operand frags: Qf[ds][e] = Q[d=ds*16+hi*8+e][q=qg] ----
    // RoPE + softmax scale folded in-register (pairs d <-> d+32 = ds <-> ds+2).
    short8 Qf[4];
    {
        const short* qrow = qbase + (size_t)qg * NQK + h * 64;
        short8 raw[4];
        #pragma unroll
        for (int ds = 0; ds < 4; ++ds)
            raw[ds] = *(const short8*)(qrow + ds * 16 + hi * 8);
        const float qs = 0.125f * 1.44269504f;  // 1/sqrt(64)*log2(e)
        float t2 = (float)(qg + poff[0]);
        #pragma unroll
        for (int ds = 0; ds < 2; ++ds)
            #pragma unroll
            for (int j = 0; j < 8; ++j) {
                int p = ds * 16 + hi * 8 + j;
                float invf = exp2f(-0.415241012f * (float)p);
                float ang = t2 * invf;
                float sn, cs;
                __sincosf(ang, &sn, &cs);
                float x1 = bf2f(raw[ds][j]), x2 = bf2f(raw[ds + 2][j]);
                Qf[ds][j]     = f2bf(qs * (x1 * cs - x2 * sn));
                Qf[ds + 2][j] = f2bf(qs * (x2 * cs + x1 * sn));
            }
    }

    short8 ones8;
    #pragma unroll
    for (int i = 0; i < 8; ++i) ones8[i] = (short)0x3F80;  // bf16 1.0

    floatx16 O0 = {}, O1 = {}, lacc = {};

    const int sr = tid >> 3;     // 0..31
    const int cc = tid & 7;

    auto stage = [&](int kt2, int buf2) {
        const int k0s = kt2 * 64;
        #pragma unroll
        for (int i = 0; i < 2; ++i) {
            int r  = i * 32 + sr;
            int gc = cc ^ (r & 7) ^ ((r >> 3) & 3);
            gload_lds16(kptr + (size_t)(k0s + r) * NQK + gc * 8,
                        (char*)(&Ks[buf2][0]) + (i * 256 + tid) * 16);
            gload_lds16(vptr + (size_t)r * NTOK + k0s + gc * 8,
                        (char*)(&Vs[buf2][0]) + (i * 256 + tid) * 16);
        }
    };

    // swizzle key: same for rows ql and ql+32 (f(r)=f(r+32))
    const int sw2 = (ql & 7) ^ ((ql >> 3) & 3);

    auto tile = [&](int kt, int buf) {
        const int k0 = kt * 64;
        if (k0 > qwb + 31) return;               // wave fully masked
        const bool anymask = (k0 + 63 > qwb);
        floatx16 s0 = {}, s1 = {};
        __builtin_amdgcn_s_setprio(1);
        #pragma unroll
        for (int ds = 0; ds < 4; ++ds) {
            int ch = ((ds * 2 + hi) ^ sw2) * 8;
            short8 kf0 = *(const short8*)&Ks[buf][ql * 64 + ch];
            short8 kf1 = *(const short8*)&Ks[buf][(32 + ql) * 64 + ch];
            s0 = __builtin_amdgcn_mfma_f32_32x32x16_bf16(kf0, Qf[ds], s0, 0, 0, 0);
            s1 = __builtin_amdgcn_mfma_f32_32x32x16_bf16(kf1, Qf[ds], s1, 0, 0, 0);
        }
        __builtin_amdgcn_s_setprio(0);
        // exp2 + causal mask, in place
        #pragma unroll
        for (int r = 0; r < 16; ++r) {
            float v0 = exp2f(s0[r]);
            float v1 = exp2f(s1[r]);
            if (anymask) {
                int ko = k0 + (r >> 2) * 8 + hi * 4 + (r & 3);
                if (ko > qg)      v0 = 0.f;
                if (ko + 32 > qg) v1 = 0.f;
            }
            s0[r] = v0; s1[r] = v1;
        }
        // PV: B-frag for step s = pack(E0[4s..4s+3], E1[4s..4s+3]) (pi-match)
        __builtin_amdgcn_s_setprio(1);
        #pragma unroll
        for (int s = 0; s < 4; ++s) {
            uint4 u = { packhi(s0[4*s+0], s0[4*s+1]), packhi(s0[4*s+2], s0[4*s+3]),
                        packhi(s1[4*s+0], s1[4*s+1]), packhi(s1[4*s+2], s1[4*s+3]) };
            short8 bp = __builtin_bit_cast(short8, u);
            int ch = ((s * 2 + hi) ^ sw2) * 8;
            short8 vf0 = *(const short8*)&Vs[buf][ql * 64 + ch];
            short8 vf1 = *(const short8*)&Vs[buf][(32 + ql) * 64 + ch];
            O0   = __builtin_amdgcn_mfma_f32_32x32x16_bf16(vf0,   bp, O0,   0, 0, 0);
            O1   = __builtin_amdgcn_mfma_f32_32x32x16_bf16(vf1,   bp, O1,   0, 0, 0);
            lacc = __builtin_amdgcn_mfma_f32_32x32x16_bf16(ones8, bp, lacc, 0, 0, 0);
        }
        __builtin_amdgcn_s_setprio(0);
    };

    // drain Q loads so counted vmcnt below sees only stage loads
    asm volatile("s_waitcnt vmcnt(0)" ::: "memory");
    stage(kt0, 0);
    if (kt0 + 1 < kt1) stage(kt0 + 1, 1);
    for (int kt = kt0; kt < kt1; ++kt) {
        const int it = kt - kt0;
        const int buf = it % 3;
        if (kt + 1 < kt1) asm volatile("s_waitcnt vmcnt(4)" ::: "memory");
        else              asm volatile("s_waitcnt vmcnt(0)" ::: "memory");
        asm volatile("s_barrier" ::: "memory");
        if (kt + 2 < kt1) stage(kt + 2, (it + 2) % 3);
        tile(kt, buf);
    }

    if (pslot >= 0) {
        float* op = Opart + (size_t)pslot * 8192;
        const int qb = w * 32 + ql;
        #pragma unroll
        for (int r = 0; r < 16; ++r) {
            int d = (r & 3) + 8 * (r >> 2) + 4 * hi;
            op[d * 128 + qb]        = O0[r];
            op[(32 + d) * 128 + qb] = O1[r];
        }
        if (hi == 0) lpart[pslot * 128 + qb] = lacc[0];
        return;
    }
    // direct path: every lane has l(q=qg) in lacc[0]; O regs map to
    // d = dblk*32 + q4*8 + hi*4 + (r&3) -> contiguous short4 stores.
    float linv = 1.0f / lacc[0];
    short* ob = attn + (size_t)(b * S_ + qg) * D_ + h * 64;
    #pragma unroll
    for (int q4 = 0; q4 < 4; ++q4) {
        short4 a = { f2bf(O0[q4*4+0] * linv), f2bf(O0[q4*4+1] * linv),
                     f2bf(O0[q4*4+2] * linv), f2bf(O0[q4*4+3] * linv) };
        *(short4*)&ob[q4 * 8 + hi * 4] = a;
        short4 c = { f2bf(O1[q4*4+0] * linv), f2bf(O1[q4*4+1] * linv),
                     f2bf(O1[q4*4+2] * linv), f2bf(O1[q4*4+3] * linv) };
        *(short4*)&ob[32 + q4 * 8 + hi * 4] = c;
    }
}

// ---------------- merge split-k partials: 256 blocks (bh, Cm) --------------
// XCD-local remap matching attn: block bid -> bh === (bid&7) (mod 8), so
// Opart reads hit the L2 of the XCD that wrote them.
__global__ __launch_bounds__(256) void attn_merge_kernel(
    const float* __restrict__ Opart, const float* __restrict__ lpart,
    short* __restrict__ attn)
{
    __shared__ float Ot[64 * 129];
    __shared__ float ls[128];
    const int bid = blockIdx.x;
    const int x = bid & 7, m = bid >> 3;      // m 0..31
    const int bh = x + 8 * (m & 3);
    const int Cm = m >> 2;                    // 0..7
    const int h = bh & 15, b = bh >> 4;
    const int C = 8 + Cm;
    const int p0 = (bh * 8 + Cm) * 2;
    const int tid = threadIdx.x;

    if (tid < 128)
        ls[tid] = lpart[p0 * 128 + tid] + lpart[(p0 + 1) * 128 + tid];
    __syncthreads();

    const float* o0 = Opart + (size_t)p0 * 8192;
    const float* o1 = o0 + 8192;
    int d = tid >> 2, q0 = (tid & 3) * 32;
    #pragma unroll
    for (int j = 0; j < 8; ++j) {
        int off = d * 128 + q0 + j * 4;
        float4 a  = *(const float4*)(o0 + off);
        float4 bv = *(const float4*)(o1 + off);
        Ot[d * 129 + q0 + j * 4 + 0] = (a.x + bv.x) / ls[q0 + j * 4 + 0];
        Ot[d * 129 + q0 + j * 4 + 1] = (a.y + bv.y) / ls[q0 + j * 4 + 1];
        Ot[d * 129 + q0 + j * 4 + 2] = (a.z + bv.z) / ls[q0 + j * 4 + 2];
        Ot[d * 129 + q0 + j * 4 + 3] = (a.w + bv.w) / ls[q0 + j * 4 + 3];
    }
    __syncthreads();
    int q = tid & 127, halfd = tid >> 7;
    alignas(16) short vals[32];
    #pragma unroll
    for (int j = 0; j < 32; ++j)
        vals[j] = f2bf(Ot[(halfd * 32 + j) * 129 + q]);
    short* ob = attn + (size_t)(b * S_ + C * 128 + q) * D_ + h * 64 + halfd * 32;
    *(uint4*)&ob[0]  = *(const uint4*)&vals[0];
    *(uint4*)&ob[8]  = *(const uint4*)&vals[8];
    *(uint4*)&ob[16] = *(const uint4*)&vals[16];
    *(uint4*)&ob[24] = *(const uint4*)&vals[24];
}

extern "C" void kernel_launch(void* const* d_in, const int* in_sizes, int n_in,
                              void* d_out, int out_size, void* d_ws, size_t ws_size,
                              hipStream_t stream) {
    const float* x  = (const float*)d_in[0];
    const float* Wq = (const float*)d_in[1];
    const float* Wk = (const float*)d_in[2];
    const float* Wv = (const float*)d_in[3];
    const float* Wo = (const float*)d_in[4];
    const int* poff = (const int*)d_in[5];
    float* out = (float*)d_out;

    short* xb  = (short*)d_ws;                      // [4096][1024]
    short* wt  = xb  + (size_t)NTOK * D_;           // [1536][1024] fused Wqkv^T
    short* woT = wt  + (size_t)NQKV * D_;           // [1024][1024] Wo^T
    short* qkb = woT + (size_t)D_ * D_;             // [4096][1280]
    short* vbT = qkb + (size_t)NTOK * NQK;          // [256][4096] pi^-1-permuted
    short* ab  = vbT + (size_t)(HKV_*DH_) * NTOK;   // [4096][1024]
    float* Opart = (float*)(ab + (size_t)NTOK * D_); // [512][64][128] fp32
    float* lpart = Opart + (size_t)512 * 8192;       // [512][128] fp32

    prep_kernel<<<dim3(4096 + 1024 + 256 + 256 + 1024), 256, 0, stream>>>(
        x, Wq, Wk, Wv, Wo, xb, wt, woT);
    gemm_tn_kernel<2><<<dim3(NQKV / 128, NTOK / 64), 256, 0, stream>>>(
        xb, wt, qkb, nullptr, vbT, NQK, poff);
    attn_kernel14<<<dim3(768), 256, 0, stream>>>(qkb, vbT, ab, Opart, lpart, poff);
    attn_merge_kernel<<<dim3(256), 256, 0, stream>>>(Opart, lpart, ab);
    gemm_tn_kernel<1><<<dim3(D_ / 128, NTOK / 64), 256, 0, stream>>>(
        ab, woT, nullptr, out, nullptr, D_, poff);
}

// Round 14
// 171.535 us; speedup vs baseline: 1.1528x; 1.0050x over previous
//
#include <hip/hip_runtime.h>
#include <hip/hip_bf16.h>
#include <math.h>

#define B_ 2
#define S_ 2048
#define D_ 1024
#define H_ 16
#define HKV_ 4
#define DH_ 64
#define NTOK (B_*S_)     // 4096
#define NQK 1280         // q(1024) + k(256) fused cols
#define NQKV 1536        // + v

typedef __attribute__((ext_vector_type(8))) short short8;
typedef __attribute__((ext_vector_type(4))) float floatx4;
typedef __attribute__((ext_vector_type(16))) float floatx16;

__device__ __forceinline__ short f2bf(float f) {
    union { __hip_bfloat16 h; short s; } u;
    u.h = __float2bfloat16(f);
    return u.s;
}
__device__ __forceinline__ float bf2f(short s) {
    union { __hip_bfloat16 h; short t; } u;
    u.t = s;
    return __bfloat162float(u.h);
}
__device__ __forceinline__ unsigned fbits(float f) {
    union { float f; unsigned u; } u; u.f = f; return u.u;
}
// pack hi16(a) | hi16(b)<<16 in ONE v_perm_b32 (RTZ bf16 truncation)
__device__ __forceinline__ unsigned packhi(float a, float b) {
    return __builtin_amdgcn_perm(fbits(b), fbits(a), 0x07060302u);
}

__device__ __forceinline__ void gload_lds16(const void* g, void* l) {
    __builtin_amdgcn_global_load_lds(
        (const __attribute__((address_space(1))) void*)g,
        (__attribute__((address_space(3))) void*)l, 16, 0, 0);
}

// ---------------- fused prep: x->bf16 convert + 4 weight transposes --------
__global__ __launch_bounds__(256) void prep_kernel(
    const float* __restrict__ x,  const float* __restrict__ Wq,
    const float* __restrict__ Wk, const float* __restrict__ Wv,
    const float* __restrict__ Wo,
    short* __restrict__ xb, short* __restrict__ wt, short* __restrict__ woT)
{
    int bid = blockIdx.x;
    if (bid < 4096) {
        int i = bid * 256 + threadIdx.x;
        float4 v = ((const float4*)x)[i];
        short4 o = { f2bf(v.x), f2bf(v.y), f2bf(v.z), f2bf(v.w) };
        ((short4*)xb)[i] = o;
        return;
    }
    bid -= 4096;
    const float* src; short* dst; int N;
    if (bid < 1024)      { src = Wq; dst = wt;                        N = 1024; }
    else if (bid < 1280) { bid -= 1024; src = Wk; dst = wt + (size_t)1024 * 1024; N = 256; }
    else if (bid < 1536) { bid -= 1280; src = Wv; dst = wt + (size_t)1280 * 1024; N = 256; }
    else                 { bid -= 1536; src = Wo; dst = woT;          N = 1024; }
    __shared__ float t[32][33];
    int tiles_n = N / 32;
    int n0 = (bid % tiles_n) * 32, k0 = (bid / tiles_n) * 32;
    int tx = threadIdx.x & 31, ty = threadIdx.x >> 5;
    #pragma unroll
    for (int i = 0; i < 4; ++i)
        t[ty + 8 * i][tx] = src[(size_t)(k0 + ty + 8 * i) * N + n0 + tx];
    __syncthreads();
    #pragma unroll
    for (int i = 0; i < 4; ++i)
        dst[(size_t)(n0 + ty + 8 * i) * 1024 + k0 + tx] = f2bf(t[tx][ty + 8 * i]);
}

// ---------------- GEMM: C[M,N] = A[M,1024] @ Bt[N,1024]^T (bf16 MFMA) -------
// 64x128 tile, BK=32, 256 thr = 4 waves as 2x2 -> wave 32 rows x 64 cols
// (acc 2x4). 3-stage LDS ring, counted vmcnt(3). Both-sides chunk swizzle
// (c ^ ((r>>1)&3)) keeps ds_read 2-way (free).
// T1 XCD swizzle: consecutive jobs (same A-row panel) pinned to one XCD ->
// per-XCD working set ~= A 1MB + B 3MB ~= L2 size. Grids divisible by 8.
// MODE 2: K region fuses RoPE in-register in the epilogue; V region stores
// transposed with pi^-1 token permutation (attn PV B-operand pure-register).
template<int MODE>
__global__ __launch_bounds__(256, 4) void gemm_tn_kernel(
    const short* __restrict__ A, const short* __restrict__ Bt,
    short* __restrict__ Cb, float* __restrict__ Cf, short* __restrict__ Ct,
    int ldc, const int* __restrict__ poff)
{
    __shared__ short As[3][64 * 32];
    __shared__ short Bs[3][128 * 32];
    const int K = 1024;
    const int tid = threadIdx.x;

    // XCD-aware job remap (bijective: nwg % 8 == 0 for both grids)
    const int id  = blockIdx.y * gridDim.x + blockIdx.x;
    const int nwg = gridDim.x * gridDim.y;
    const int per = nwg >> 3;
    const int job = (id & 7) * per + (id >> 3);
    const int bm0 = (job / gridDim.x) * 64;
    const int bn0 = (job % gridDim.x) * 128;

    const int lane = tid & 63, w = tid >> 6;
    const int wm = (w >> 1) * 32, wn = (w & 1) * 64;
    const int lm = lane & 15, quad = lane >> 4;

    floatx4 acc[2][4] = {};

    const int r0  = tid >> 2;                       // staged row 0..63
    const int kb0 = (((tid & 3) ^ ((r0 >> 1) & 3)) ) * 16;  // swizzled src chunk (bytes)

    auto stage = [&](int kt, int buf) {
        const char* gaA = (const char*)A  + ((size_t)(bm0 + r0) * K + kt) * 2 + kb0;
        const char* gaB = (const char*)Bt + ((size_t)(bn0 + r0) * K + kt) * 2 + kb0;
        gload_lds16(gaA,                      (char*)As[buf] + tid * 16);
        gload_lds16(gaB,                      (char*)Bs[buf] + tid * 16);
        gload_lds16(gaB + (size_t)64 * K * 2, (char*)Bs[buf] + 4096 + tid * 16);
    };

    const int swr = (lm >> 1) & 3;

    stage(0, 0);
    stage(32, 1);
    for (int kt = 0; kt < K; kt += 32) {
        const int it = kt >> 5;
        const int buf = it % 3;
        if (it < (K / 32) - 1) asm volatile("s_waitcnt vmcnt(3)" ::: "memory");
        else                   asm volatile("s_waitcnt vmcnt(0)" ::: "memory");
        asm volatile("s_barrier" ::: "memory");
        if (kt + 64 < K) stage(kt + 64, (it + 2) % 3);

        short8 af[2], bfr[4];
        #pragma unroll
        for (int mt = 0; mt < 2; ++mt)
            af[mt] = *(const short8*)&As[buf][(wm + mt * 16 + lm) * 32 + ((quad ^ swr) * 8)];
        #pragma unroll
        for (int nt = 0; nt < 4; ++nt)
            bfr[nt] = *(const short8*)&Bs[buf][(wn + nt * 16 + lm) * 32 + ((quad ^ swr) * 8)];
        #pragma unroll
        for (int mt = 0; mt < 2; ++mt)
            #pragma unroll
            for (int nt = 0; nt < 4; ++nt)
                acc[mt][nt] = __builtin_amdgcn_mfma_f32_16x16x32_bf16(
                    af[mt], bfr[nt], acc[mt][nt], 0, 0, 0);
    }

    const int col_base = bn0 + wn;
    const int row_base = bm0 + wm;
    if (MODE == 2 && bn0 >= NQK) {  // V tiles -> transposed, pi^-1-permuted store
        #pragma unroll
        for (int mt = 0; mt < 2; ++mt)
            #pragma unroll
            for (int nt = 0; nt < 4; ++nt) {
                int vcol = col_base + nt * 16 + lm - NQK;
                int row0 = row_base + mt * 16 + quad * 4;
                // pi^-1 within 64: bit2 = old bit5, bits3..5 = old bits2..4
                int prow = (row0 & ~60) | ((row0 & 32) >> 3) | ((row0 & 0x1C) << 1);
                short4 o = { f2bf(acc[mt][nt][0]), f2bf(acc[mt][nt][1]),
                             f2bf(acc[mt][nt][2]), f2bf(acc[mt][nt][3]) };
                *(short4*)&Ct[(size_t)vcol * NTOK + prow] = o;
            }
    } else if (MODE == 1) {
        #pragma unroll
        for (int mt = 0; mt < 2; ++mt)
            #pragma unroll
            for (int nt = 0; nt < 4; ++nt)
                #pragma unroll
                for (int r = 0; r < 4; ++r) {
                    int row = row_base + mt * 16 + quad * 4 + r;
                    int col = col_base + nt * 16 + lm;
                    Cf[(size_t)row * ldc + col] = acc[mt][nt][r];
                }
    } else {
        if (MODE == 2 && bn0 >= 1024) {
            // K region: fused RoPE. p = nt*16+lm (<32) pairs with p+32 = nt+2.
            #pragma unroll
            for (int mt = 0; mt < 2; ++mt)
                #pragma unroll
                for (int r = 0; r < 4; ++r) {
                    int row = row_base + mt * 16 + quad * 4 + r;
                    float t = (float)((row & (S_ - 1)) + poff[0]);
                    #pragma unroll
                    for (int nt = 0; nt < 2; ++nt) {
                        int p = nt * 16 + lm;
                        float invf = exp2f(-0.415241012f * (float)p);
                        float ang = t * invf;
                        float sn, cs;
                        __sincosf(ang, &sn, &cs);
                        float x1 = acc[mt][nt][r], x2 = acc[mt][nt + 2][r];
                        acc[mt][nt][r]     = x1 * cs - x2 * sn;
                        acc[mt][nt + 2][r] = x2 * cs + x1 * sn;
                    }
                }
        }
        #pragma unroll
        for (int mt = 0; mt < 2; ++mt)
            #pragma unroll
            for (int nt = 0; nt < 4; ++nt)
                #pragma unroll
                for (int r = 0; r < 4; ++r) {
                    int row = row_base + mt * 16 + quad * 4 + r;
                    int col = col_base + nt * 16 + lm;
                    Cb[(size_t)row * ldc + col] = f2bf(acc[mt][nt][r]);
                }
    }
}

// ---------------- Flash attention v15: XCD-local + two-tile pipeline -------
// v14's XCD-local (b,h) mapping, plus T15: QK^T of tile kt+1 (pure MFMA)
// placed in the same straight-line region as exp/pack/PV of tile kt
// (VALU+MFMA on independent chains) -> MFMA and VALU pipes overlap.
// Score state in named p0/p1 -> n0/n1 (no runtime-indexed arrays).
// Ring audit: stage(kt+2) writes buf[(kt-1)%3] whose readers ran before this
// barrier; QK(kt+1) needs stage(kt+1) drained -> vmcnt(0) before barrier
// (one stage in flight there; it had a full tile-compute to land, L2-local).
__global__ __launch_bounds__(256, 3) void attn_kernel15(
    const short* __restrict__ qk,  // [NTOK][1280], K cols pre-roped
    const short* __restrict__ vT,  // [256][NTOK] pi^-1-permuted tokens
    short* __restrict__ attn,      // [NTOK][1024]
    float* __restrict__ Opart,     // [512][64][128]
    float* __restrict__ lpart,     // [512][128]
    const int* __restrict__ poff)
{
    __shared__ short Ks[3][64 * 64];
    __shared__ short Vs[3][64 * 64];

    const int tid = threadIdx.x;
    const int lane = tid & 63, w = tid >> 6;
    const int ql = lane & 31, hi = lane >> 5;

    const int jid = blockIdx.x;
    const int x = jid & 7, m = jid >> 3;
    const int bh = x + 8 * (m & 3);
    const int rest = m >> 2;            // 0..23
    const int role = rest >> 3;         // 0,1 = split halves; 2 = direct
    const int t = rest & 7;
    int C, kt0, kt1, pslot;
    if (role < 2) {                     // split jobs: C = 8..15
        C = 15 - t;
        kt0 = role ? (C + 1) : 0;
        kt1 = role ? (2 * C + 2) : (C + 1);
        pslot = (bh * 8 + (7 - t)) * 2 + role;
    } else {                            // direct jobs: C = 0..7
        C = t;
        kt0 = 0; kt1 = 2 * C + 2; pslot = -1;
    }
    const int h = bh & 15, b = bh >> 4, g = h >> 2;
    const int qwb = C * 128 + w * 32;    // wave q base within batch
    const int qg  = qwb + ql;            // this lane's q row

    const short* qbase = qk + (size_t)b * S_ * NQK;
    const short* kptr  = qbase + 1024 + g * 64;
    const short* vptr  = vT + (size_t)g * 64 * NTOK + (size_t)b * S_;

    // ---- Q as B-operand frags: Qf[ds][e] = Q[d=ds*16+hi*8+e][q=qg] ----
    short8 Qf[4];
    {
        const short* qrow = qbase + (size_t)qg * NQK + h * 64;
        short8 raw[4];
        #pragma unroll
        for (int ds = 0; ds < 4; ++ds)
            raw[ds] = *(const short8*)(qrow + ds * 16 + hi * 8);
        const float qs = 0.125f * 1.44269504f;  // 1/sqrt(64)*log2(e)
        float t2 = (float)(qg + poff[0]);
        #pragma unroll
        for (int ds = 0; ds < 2; ++ds)
            #pragma unroll
            for (int j = 0; j < 8; ++j) {
                int p = ds * 16 + hi * 8 + j;
                float invf = exp2f(-0.415241012f * (float)p);
                float ang = t2 * invf;
                float sn, cs;
                __sincosf(ang, &sn, &cs);
                float x1 = bf2f(raw[ds][j]), x2 = bf2f(raw[ds + 2][j]);
                Qf[ds][j]     = f2bf(qs * (x1 * cs - x2 * sn));
                Qf[ds + 2][j] = f2bf(qs * (x2 * cs + x1 * sn));
            }
    }

    short8 ones8;
    #pragma unroll
    for (int i = 0; i < 8; ++i) ones8[i] = (short)0x3F80;  // bf16 1.0

    floatx16 O0 = {}, O1 = {}, lacc = {};

    const int sr = tid >> 3;     // 0..31
    const int cc = tid & 7;

    auto stage = [&](int kt2, int buf2) {
        const int k0s = kt2 * 64;
        #pragma unroll
        for (int i = 0; i < 2; ++i) {
            int r  = i * 32 + sr;
            int gc = cc ^ (r & 7) ^ ((r >> 3) & 3);
            gload_lds16(kptr + (size_t)(k0s + r) * NQK + gc * 8,
                        (char*)(&Ks[buf2][0]) + (i * 256 + tid) * 16);
            gload_lds16(vptr + (size_t)r * NTOK + k0s + gc * 8,
                        (char*)(&Vs[buf2][0]) + (i * 256 + tid) * 16);
        }
    };

    // swizzle key: same for rows ql and ql+32 (f(r)=f(r+32))
    const int sw2 = (ql & 7) ^ ((ql >> 3) & 3);

    auto qk_tile = [&](int buf, floatx16& s0, floatx16& s1) {
        floatx16 a0 = {}, a1 = {};
        #pragma unroll
        for (int ds = 0; ds < 4; ++ds) {
            int ch = ((ds * 2 + hi) ^ sw2) * 8;
            short8 kf0 = *(const short8*)&Ks[buf][ql * 64 + ch];
            short8 kf1 = *(const short8*)&Ks[buf][(32 + ql) * 64 + ch];
            a0 = __builtin_amdgcn_mfma_f32_32x32x16_bf16(kf0, Qf[ds], a0, 0, 0, 0);
            a1 = __builtin_amdgcn_mfma_f32_32x32x16_bf16(kf1, Qf[ds], a1, 0, 0, 0);
        }
        s0 = a0; s1 = a1;
    };

    auto finish_tile = [&](int kt, int buf, floatx16 s0, floatx16 s1) {
        const int k0 = kt * 64;
        const bool anymask = (k0 + 63 > qwb);
        #pragma unroll
        for (int r = 0; r < 16; ++r) {
            float v0 = exp2f(s0[r]);
            float v1 = exp2f(s1[r]);
            if (anymask) {
                int ko = k0 + (r >> 2) * 8 + hi * 4 + (r & 3);
                if (ko > qg)      v0 = 0.f;
                if (ko + 32 > qg) v1 = 0.f;
            }
            s0[r] = v0; s1[r] = v1;
        }
        #pragma unroll
        for (int s = 0; s < 4; ++s) {
            uint4 u = { packhi(s0[4*s+0], s0[4*s+1]), packhi(s0[4*s+2], s0[4*s+3]),
                        packhi(s1[4*s+0], s1[4*s+1]), packhi(s1[4*s+2], s1[4*s+3]) };
            short8 bp = __builtin_bit_cast(short8, u);
            int ch = ((s * 2 + hi) ^ sw2) * 8;
            short8 vf0 = *(const short8*)&Vs[buf][ql * 64 + ch];
            short8 vf1 = *(const short8*)&Vs[buf][(32 + ql) * 64 + ch];
            O0   = __builtin_amdgcn_mfma_f32_32x32x16_bf16(vf0,   bp, O0,   0, 0, 0);
            O1   = __builtin_amdgcn_mfma_f32_32x32x16_bf16(vf1,   bp, O1,   0, 0, 0);
            lacc = __builtin_amdgcn_mfma_f32_32x32x16_bf16(ones8, bp, lacc, 0, 0, 0);
        }
    };

    // prologue: 2-ahead stage, compute QK(kt0)
    asm volatile("s_waitcnt vmcnt(0)" ::: "memory");
    stage(kt0, 0);
    stage(kt0 + 1, 1);
    asm volatile("s_waitcnt vmcnt(4)" ::: "memory");
    asm volatile("s_barrier" ::: "memory");
    floatx16 p0, p1;
    qk_tile(0, p0, p1);   // kt0 never fully masked for any wave

    for (int kt = kt0; kt < kt1; ++kt) {
        const int it = kt - kt0;
        asm volatile("s_waitcnt vmcnt(0)" ::: "memory");
        asm volatile("s_barrier" ::: "memory");
        if (kt + 2 < kt1) stage(kt + 2, (it + 2) % 3);

        const bool cvalid = (kt * 64 <= qwb + 31);
        const bool nvalid = (kt + 1 < kt1) && ((kt + 1) * 64 <= qwb + 31);
        floatx16 n0, n1;
        __builtin_amdgcn_s_setprio(1);
        if (nvalid && cvalid) {
            // hot path: straight-line, independent chains -> pipes overlap
            qk_tile((it + 1) % 3, n0, n1);
            finish_tile(kt, it % 3, p0, p1);
        } else {
            if (nvalid) qk_tile((it + 1) % 3, n0, n1);
            if (cvalid) finish_tile(kt, it % 3, p0, p1);
        }
        __builtin_amdgcn_s_setprio(0);
        p0 = n0; p1 = n1;
    }

    if (pslot >= 0) {
        float* op = Opart + (size_t)pslot * 8192;
        const int qb = w * 32 + ql;
        #pragma unroll
        for (int r = 0; r < 16; ++r) {
            int d = (r & 3) + 8 * (r >> 2) + 4 * hi;
            op[d * 128 + qb]        = O0[r];
            op[(32 + d) * 128 + qb] = O1[r];
        }
        if (hi == 0) lpart[pslot * 128 + qb] = lacc[0];
        return;
    }
    // direct path: every lane has l(q=qg) in lacc[0]; O regs map to
    // d = dblk*32 + q4*8 + hi*4 + (r&3) -> contiguous short4 stores.
    float linv = 1.0f / lacc[0];
    short* ob = attn + (size_t)(b * S_ + qg) * D_ + h * 64;
    #pragma unroll
    for (int q4 = 0; q4 < 4; ++q4) {
        short4 a = { f2bf(O0[q4*4+0] * linv), f2bf(O0[q4*4+1] * linv),
                     f2bf(O0[q4*4+2] * linv), f2bf(O0[q4*4+3] * linv) };
        *(short4*)&ob[q4 * 8 + hi * 4] = a;
        short4 c = { f2bf(O1[q4*4+0] * linv), f2bf(O1[q4*4+1] * linv),
                     f2bf(O1[q4*4+2] * linv), f2bf(O1[q4*4+3] * linv) };
        *(short4*)&ob[32 + q4 * 8 + hi * 4] = c;
    }
}

// ---------------- merge split-k partials: 256 blocks (bh, Cm) --------------
// XCD-local remap matching attn: block bid -> bh === (bid&7) (mod 8), so
// Opart reads hit the L2 of the XCD that wrote them.
__global__ __launch_bounds__(256) void attn_merge_kernel(
    const float* __restrict__ Opart, const float* __restrict__ lpart,
    short* __restrict__ attn)
{
    __shared__ float Ot[64 * 129];
    __shared__ float ls[128];
    const int bid = blockIdx.x;
    const int x = bid & 7, m = bid >> 3;      // m 0..31
    const int bh = x + 8 * (m & 3);
    const int Cm = m >> 2;                    // 0..7
    const int h = bh & 15, b = bh >> 4;
    const int C = 8 + Cm;
    const int p0 = (bh * 8 + Cm) * 2;
    const int tid = threadIdx.x;

    if (tid < 128)
        ls[tid] = lpart[p0 * 128 + tid] + lpart[(p0 + 1) * 128 + tid];
    __syncthreads();

    const float* o0 = Opart + (size_t)p0 * 8192;
    const float* o1 = o0 + 8192;
    int d = tid >> 2, q0 = (tid & 3) * 32;
    #pragma unroll
    for (int j = 0; j < 8; ++j) {
        int off = d * 128 + q0 + j * 4;
        float4 a  = *(const float4*)(o0 + off);
        float4 bv = *(const float4*)(o1 + off);
        Ot[d * 129 + q0 + j * 4 + 0] = (a.x + bv.x) / ls[q0 + j * 4 + 0];
        Ot[d * 129 + q0 + j * 4 + 1] = (a.y + bv.y) / ls[q0 + j * 4 + 1];
        Ot[d * 129 + q0 + j * 4 + 2] = (a.z + bv.z) / ls[q0 + j * 4 + 2];
        Ot[d * 129 + q0 + j * 4 + 3] = (a.w + bv.w) / ls[q0 + j * 4 + 3];
    }
    __syncthreads();
    int q = tid & 127, halfd = tid >> 7;
    alignas(16) short vals[32];
    #pragma unroll
    for (int j = 0; j < 32; ++j)
        vals[j] = f2bf(Ot[(halfd * 32 + j) * 129 + q]);
    short* ob = attn + (size_t)(b * S_ + C * 128 + q) * D_ + h * 64 + halfd * 32;
    *(uint4*)&ob[0]  = *(const uint4*)&vals[0];
    *(uint4*)&ob[8]  = *(const uint4*)&vals[8];
    *(uint4*)&ob[16] = *(const uint4*)&vals[16];
    *(uint4*)&ob[24] = *(const uint4*)&vals[24];
}

extern "C" void kernel_launch(void* const* d_in, const int* in_sizes, int n_in,
                              void* d_out, int out_size, void* d_ws, size_t ws_size,
                              hipStream_t stream) {
    const float* x  = (const float*)d_in[0];
    const float* Wq = (const float*)d_in[1];
    const float* Wk = (const float*)d_in[2];
    const float* Wv = (const float*)d_in[3];
    const float* Wo = (const float*)d_in[4];
    const int* poff = (const int*)d_in[5];
    float* out = (float*)d_out;

    short* xb  = (short*)d_ws;                      // [4096][1024]
    short* wt  = xb  + (size_t)NTOK * D_;           // [1536][1024] fused Wqkv^T
    short* woT = wt  + (size_t)NQKV * D_;           // [1024][1024] Wo^T
    short* qkb = woT + (size_t)D_ * D_;             // [4096][1280]
    short* vbT = qkb + (size_t)NTOK * NQK;          // [256][4096] pi^-1-permuted
    short* ab  = vbT + (size_t)(HKV_*DH_) * NTOK;   // [4096][1024]
    float* Opart = (float*)(ab + (size_t)NTOK * D_); // [512][64][128] fp32
    float* lpart = Opart + (size_t)512 * 8192;       // [512][128] fp32

    prep_kernel<<<dim3(4096 + 1024 + 256 + 256 + 1024), 256, 0, stream>>>(
        x, Wq, Wk, Wv, Wo, xb, wt, woT);
    gemm_tn_kernel<2><<<dim3(NQKV / 128, NTOK / 64), 256, 0, stream>>>(
        xb, wt, qkb, nullptr, vbT, NQK, poff);
    attn_kernel15<<<dim3(768), 256, 0, stream>>>(qkb, vbT, ab, Opart, lpart, poff);
    attn_merge_kernel<<<dim3(256), 256, 0, stream>>>(Opart, lpart, ab);
    gemm_tn_kernel<1><<<dim3(D_ / 128, NTOK / 64), 256, 0, stream>>>(
        ab, woT, nullptr, out, nullptr, D_, poff);
}